// Round 1
// baseline (3389.494 us; speedup 1.0000x reference)
//
#include <hip/hip_runtime.h>

// GraphProject: out[b,n,:] = [xyz(3) | bilerp(feat0,64) | bilerp(feat1,128)
//                             | bilerp(feat2,256) | bilerp(feat3,512)]  (963 ch)
// proj_mat is unused by the reference.

#define VPB 4  // vertices per block

// ---- prepass: (B,C,S,S) -> (B,S,S,C) channel-last for coalesced gathers ----
template<int C, int S>
__global__ __launch_bounds__(256) void transpose_feat(const float* __restrict__ src,
                                                      float* __restrict__ dst,
                                                      int total) {
    int i = blockIdx.x * 256 + threadIdx.x;
    if (i >= total) return;
    int c  = i % C;        // C pow2 -> and
    int p  = i / C;        // pow2 -> shift
    int w  = p % S;        // compile-time magic div
    int p2 = p / S;
    int h  = p2 % S;
    int b  = p2 / S;
    dst[i] = src[((b * C + c) * S + h) * S + w];
}

// ---- main: per-vertex projection + 4-scale bilinear gather ----
__global__ __launch_bounds__(256) void gp_main(const float* __restrict__ verts,
                                               const float* __restrict__ f0,
                                               const float* __restrict__ f1,
                                               const float* __restrict__ f2,
                                               const float* __restrict__ f3,
                                               float* __restrict__ out,
                                               int N, int total_v) {
    __shared__ float swt[VPB][4][4];  // w11,w12,w21,w22 per (vert, scale)
    __shared__ int   sof[VPB][4][4];  // corner element offsets (pre-mult by C)
    __shared__ float sv[VPB][3];      // xyz passthrough

    const int t  = threadIdx.x;
    const int v0 = blockIdx.x * VPB;

    if (t < VPB * 4) {
        const int v  = t >> 2;
        const int sc = t & 3;
        const int vi = v0 + v;
        if (vi < total_v) {
            const int b = vi / N;
            const float X = verts[3 * vi + 0];
            const float Y = verts[3 * vi + 1];
            const float Z = verts[3 * vi + 2];
            if (sc == 0) { sv[v][0] = X; sv[v][1] = Y; sv[v][2] = Z; }
            // h = FY*(Y/Z)+CY ; w = FX*(X/-Z)+CX  -- exact rn ops, no contraction
            const float h = __fadd_rn(__fmul_rn(250.0f, __fdiv_rn(Y, Z)), 112.0f);
            const float w = __fadd_rn(__fmul_rn(250.0f, __fdiv_rn(X, -Z)), 112.0f);

            const int   Sarr[4] = {56, 28, 14, 7};
            const int   Carr[4] = {64, 128, 256, 512};
            const float invA[4] = {0.25f, 0.125f, 0.0625f, 0.03125f};
            const int s  = Sarr[sc];
            const int Cc = Carr[sc];
            const float smax = (float)(s - 1);

            const float x = fminf(fmaxf(__fmul_rn(h, invA[sc]), 0.0f), smax);
            const float y = fminf(fmaxf(__fmul_rn(w, invA[sc]), 0.0f), smax);
            const float x1f = floorf(x), x2f = ceilf(x);
            const float y1f = floorf(y), y2f = ceilf(y);
            const int x1 = (int)x1f, x2 = (int)x2f;
            const int y1 = (int)y1f, y2 = (int)y2f;

            swt[v][sc][0] = (x2f - x) * (y2f - y);  // w11
            swt[v][sc][1] = (x2f - x) * (y - y1f);  // w12
            swt[v][sc][2] = (x - x1f) * (y2f - y);  // w21
            swt[v][sc][3] = (x - x1f) * (y - y1f);  // w22

            const int base = b * s * s;
            sof[v][sc][0] = (base + x1 * s + y1) * Cc;
            sof[v][sc][1] = (base + x1 * s + y2) * Cc;
            sof[v][sc][2] = (base + x2 * s + y1) * Cc;
            sof[v][sc][3] = (base + x2 * s + y2) * Cc;
        }
    }
    __syncthreads();

    // channel-group mapping: t<240 handles a float4 of channels
    int sc, cbase, kbase;
    const float* fp = f0;
    if (t < 16)       { sc = 0; cbase = 4 * t;         kbase = 3;   fp = f0; }
    else if (t < 48)  { sc = 1; cbase = 4 * (t - 16);  kbase = 67;  fp = f1; }
    else if (t < 112) { sc = 2; cbase = 4 * (t - 48);  kbase = 195; fp = f2; }
    else if (t < 240) { sc = 3; cbase = 4 * (t - 112); kbase = 451; fp = f3; }
    else              { sc = -1; cbase = 0; kbase = 0; }

    for (int v = 0; v < VPB; ++v) {
        const int vi = v0 + v;
        if (vi >= total_v) break;
        const size_t obase = (size_t)vi * 963;
        if (sc >= 0) {
            const float w11 = swt[v][sc][0], w12 = swt[v][sc][1];
            const float w21 = swt[v][sc][2], w22 = swt[v][sc][3];
            const float4 q11 = *(const float4*)(fp + sof[v][sc][0] + cbase);
            const float4 q12 = *(const float4*)(fp + sof[v][sc][1] + cbase);
            const float4 q21 = *(const float4*)(fp + sof[v][sc][2] + cbase);
            const float4 q22 = *(const float4*)(fp + sof[v][sc][3] + cbase);
            // ref order: w11*Q11 + w21*Q21 + w12*Q12 + w22*Q22
            float r0 = w11 * q11.x + w21 * q21.x + w12 * q12.x + w22 * q22.x;
            float r1 = w11 * q11.y + w21 * q21.y + w12 * q12.y + w22 * q22.y;
            float r2 = w11 * q11.z + w21 * q21.z + w12 * q12.z + w22 * q22.z;
            float r3 = w11 * q11.w + w21 * q21.w + w12 * q12.w + w22 * q22.w;
            float* op = out + obase + kbase + cbase;
            op[0] = r0; op[1] = r1; op[2] = r2; op[3] = r3;
        } else if (t >= 240 && t < 243) {
            out[obase + (t - 240)] = sv[v][t - 240];
        }
    }
}

extern "C" void kernel_launch(void* const* d_in, const int* in_sizes, int n_in,
                              void* d_out, int out_size, void* d_ws, size_t ws_size,
                              hipStream_t stream) {
    const float* verts = (const float*)d_in[0];
    const float* f0s   = (const float*)d_in[1];
    const float* f1s   = (const float*)d_in[2];
    const float* f2s   = (const float*)d_in[3];
    const float* f3s   = (const float*)d_in[4];
    // d_in[5] (proj_mat) unused by reference

    const int B = in_sizes[5] / 16;          // proj is B*4*4
    const int N = in_sizes[0] / (3 * B);
    const int total_v = B * N;

    const int n0 = B * 64 * 56 * 56;
    const int n1 = B * 128 * 28 * 28;
    const int n2 = B * 256 * 14 * 14;
    const int n3 = B * 512 * 7 * 7;

    float* t0 = (float*)d_ws;
    float* t1 = t0 + n0;
    float* t2 = t1 + n1;
    float* t3 = t2 + n2;

    transpose_feat<64, 56><<<(n0 + 255) / 256, 256, 0, stream>>>(f0s, t0, n0);
    transpose_feat<128, 28><<<(n1 + 255) / 256, 256, 0, stream>>>(f1s, t1, n1);
    transpose_feat<256, 14><<<(n2 + 255) / 256, 256, 0, stream>>>(f2s, t2, n2);
    transpose_feat<512, 7><<<(n3 + 255) / 256, 256, 0, stream>>>(f3s, t3, n3);

    const int nblocks = (total_v + VPB - 1) / VPB;
    gp_main<<<nblocks, 256, 0, stream>>>(verts, t0, t1, t2, t3,
                                         (float*)d_out, N, total_v);
}